// Round 1
// baseline (788.103 us; speedup 1.0000x reference)
//
#include <hip/hip_runtime.h>

#define K_FEATS 128
#define SCAN_CHUNK 1024

// ---------------- degree histogram ----------------
__global__ __launch_bounds__(256) void hist_kernel(
    const int* __restrict__ src, const int* __restrict__ dst,
    int* __restrict__ deg_out, int* __restrict__ deg_in, int ne)
{
    int stride = gridDim.x * blockDim.x;
    for (int e = blockIdx.x * blockDim.x + threadIdx.x; e < ne; e += stride) {
        atomicAdd(&deg_out[src[e]], 1);
        atomicAdd(&deg_in[dst[e]], 1);
    }
}

// ---------------- norms + row_off[n] sentinel ----------------
__global__ __launch_bounds__(256) void norms_kernel(
    const int* __restrict__ deg_out, const int* __restrict__ deg_in,
    float* __restrict__ norm_src, float* __restrict__ norm_dst,
    int* __restrict__ row_off, int n, int ne)
{
    int i = blockIdx.x * 256 + threadIdx.x;
    if (i == 0) row_off[n] = ne;
    if (i < n) {
        norm_src[i] = 1.0f / sqrtf((float)max(deg_out[i], 1));
        norm_dst[i] = 1.0f / sqrtf((float)max(deg_in[i], 1));
    }
}

// ---------------- 3-phase exclusive scan of deg_in -> row_off ----------------
__global__ __launch_bounds__(256) void scan_a(const int* __restrict__ deg,
                                              int* __restrict__ partial, int n)
{
    __shared__ int sh[256];
    int t = threadIdx.x;
    int base = blockIdx.x * SCAN_CHUNK + t * 4;
    int s = 0;
#pragma unroll
    for (int j = 0; j < 4; j++)
        if (base + j < n) s += deg[base + j];
    sh[t] = s;
    __syncthreads();
    for (int off = 128; off > 0; off >>= 1) {
        if (t < off) sh[t] += sh[t + off];
        __syncthreads();
    }
    if (t == 0) partial[blockIdx.x] = sh[0];
}

__global__ void scan_b(int* __restrict__ partial, int nb)
{
    if (threadIdx.x == 0) {
        int run = 0;
        for (int i = 0; i < nb; i++) {
            int v = partial[i];
            partial[i] = run;
            run += v;
        }
    }
}

__global__ __launch_bounds__(256) void scan_c(const int* __restrict__ deg,
                                              const int* __restrict__ partial,
                                              int* __restrict__ row_off, int n)
{
    __shared__ int sh[256];
    int t = threadIdx.x;
    int base = blockIdx.x * SCAN_CHUNK + t * 4;
    int v[4];
    int s = 0;
#pragma unroll
    for (int j = 0; j < 4; j++) {
        v[j] = (base + j < n) ? deg[base + j] : 0;
        s += v[j];
    }
    sh[t] = s;
    __syncthreads();
    for (int off = 1; off < 256; off <<= 1) {
        int x = (t >= off) ? sh[t - off] : 0;
        __syncthreads();
        sh[t] += x;
        __syncthreads();
    }
    int excl = sh[t] - s + partial[blockIdx.x];
#pragma unroll
    for (int j = 0; j < 4; j++) {
        if (base + j < n) row_off[base + j] = excl;
        excl += v[j];
    }
}

// ---------------- CSR fill ----------------
__global__ __launch_bounds__(256) void fill_csr(
    const int* __restrict__ src, const int* __restrict__ dst,
    const int* __restrict__ row_off, int* __restrict__ cursor,
    int* __restrict__ csr, int ne)
{
    int stride = gridDim.x * blockDim.x;
    for (int e = blockIdx.x * blockDim.x + threadIdx.x; e < ne; e += stride) {
        int d = dst[e];
        int p = row_off[d] + atomicAdd(&cursor[d], 1);
        csr[p] = src[e];
    }
}

// ---------------- GEMM: T = rowscale ⊙ (X @ W), K=128, M in {128,64} ----------------
template <int M>
__global__ __launch_bounds__(256) void gemm_scale(
    const float* __restrict__ X, const float* __restrict__ W,
    const float* __restrict__ scale, float* __restrict__ T, int n)
{
    constexpr int KC = 16;
    constexpr int CT = M / 8;       // col-threads: 16 (M=128) or 8 (M=64)
    constexpr int RT = 256 / CT;    // row-threads: 16 or 32
    constexpr int RPT = 128 / RT;   // rows per thread: 8 or 4
    constexpr int XPITCH = 132;     // pad: conflict-free reads, 16B-aligned

    __shared__ float Ws[K_FEATS * M];
    __shared__ float Xs[KC * XPITCH];

    int t = threadIdx.x;
    int tc = t % CT;
    int tr = t / CT;
    int block_row = blockIdx.x * 128;

    // stage full W into LDS (row-major [128][M]), contiguous float4 stores
#pragma unroll
    for (int i = 0; i < M / 8; i++) {
        int idx4 = t + i * 256;
        ((float4*)Ws)[idx4] = ((const float4*)W)[idx4];
    }

    float acc[RPT][8] = {};

    for (int k0 = 0; k0 < K_FEATS; k0 += KC) {
        // stage X chunk transposed: Xs[kk][row], 128 rows x KC cols
#pragma unroll
        for (int i = 0; i < (128 * KC) / (256 * 4); i++) {  // 2 float4 per thread
            int idx4 = t + i * 256;       // over [128][KC/4]
            int r = idx4 / (KC / 4);
            int c4 = idx4 % (KC / 4);
            int gr = block_row + r;
            float4 v = make_float4(0.f, 0.f, 0.f, 0.f);
            if (gr < n) v = *(const float4*)(X + (size_t)gr * K_FEATS + k0 + c4 * 4);
            Xs[(c4 * 4 + 0) * XPITCH + r] = v.x;
            Xs[(c4 * 4 + 1) * XPITCH + r] = v.y;
            Xs[(c4 * 4 + 2) * XPITCH + r] = v.z;
            Xs[(c4 * 4 + 3) * XPITCH + r] = v.w;
        }
        __syncthreads();
#pragma unroll 8
        for (int kk = 0; kk < KC; kk++) {
            float4 w0 = *(const float4*)&Ws[(k0 + kk) * M + 8 * tc];
            float4 w1 = *(const float4*)&Ws[(k0 + kk) * M + 8 * tc + 4];
            float xr[RPT];
#pragma unroll
            for (int g = 0; g < RPT / 4; g++) {
                float4 xa = *(const float4*)&Xs[kk * XPITCH + 4 * tr + g * (4 * RT)];
                xr[g * 4 + 0] = xa.x;
                xr[g * 4 + 1] = xa.y;
                xr[g * 4 + 2] = xa.z;
                xr[g * 4 + 3] = xa.w;
            }
#pragma unroll
            for (int i = 0; i < RPT; i++) {
                acc[i][0] += xr[i] * w0.x;
                acc[i][1] += xr[i] * w0.y;
                acc[i][2] += xr[i] * w0.z;
                acc[i][3] += xr[i] * w0.w;
                acc[i][4] += xr[i] * w1.x;
                acc[i][5] += xr[i] * w1.y;
                acc[i][6] += xr[i] * w1.z;
                acc[i][7] += xr[i] * w1.w;
            }
        }
        __syncthreads();
    }

    // epilogue: scale row by norm_src and store
#pragma unroll
    for (int i = 0; i < RPT; i++) {
        int r = block_row + 4 * tr + (i & 3) + (i >> 2) * (4 * RT);
        if (r < n) {
            float s = scale[r];
            float4 o0 = make_float4(acc[i][0] * s, acc[i][1] * s, acc[i][2] * s, acc[i][3] * s);
            float4 o1 = make_float4(acc[i][4] * s, acc[i][5] * s, acc[i][6] * s, acc[i][7] * s);
            *(float4*)(T + (size_t)r * M + 8 * tc) = o0;
            *(float4*)(T + (size_t)r * M + 8 * tc + 4) = o1;
        }
    }
}

// ---------------- aggregation: out[v] = act( ndst[v]*sum_{u in N(v)} T[u] + b ) ----------------
template <bool RELU>
__global__ __launch_bounds__(256) void aggregate4(
    const float* __restrict__ Tm, const int* __restrict__ row_off,
    const int* __restrict__ csr, const float* __restrict__ ndst,
    const float* __restrict__ bias, float* __restrict__ out, int n)
{
    int lane = threadIdx.x & 31;
    int team = threadIdx.x >> 5;
    int fb = lane * 4;
    float4 b = *(const float4*)(bias + fb);
    int stride = gridDim.x * 8;
    for (int v = blockIdx.x * 8 + team; v < n; v += stride) {
        int s = row_off[v], e = row_off[v + 1];
        float nd = ndst[v];
        float ax = 0.f, ay = 0.f, az = 0.f, aw = 0.f;
        int i = s;
        for (; i + 4 <= e; i += 4) {
            int u0 = csr[i], u1 = csr[i + 1], u2 = csr[i + 2], u3 = csr[i + 3];
            float4 t0 = *(const float4*)(Tm + (size_t)u0 * 128 + fb);
            float4 t1 = *(const float4*)(Tm + (size_t)u1 * 128 + fb);
            float4 t2 = *(const float4*)(Tm + (size_t)u2 * 128 + fb);
            float4 t3 = *(const float4*)(Tm + (size_t)u3 * 128 + fb);
            ax += (t0.x + t1.x) + (t2.x + t3.x);
            ay += (t0.y + t1.y) + (t2.y + t3.y);
            az += (t0.z + t1.z) + (t2.z + t3.z);
            aw += (t0.w + t1.w) + (t2.w + t3.w);
        }
        for (; i < e; i++) {
            int u = csr[i];
            float4 t0 = *(const float4*)(Tm + (size_t)u * 128 + fb);
            ax += t0.x; ay += t0.y; az += t0.z; aw += t0.w;
        }
        float4 o;
        o.x = nd * ax + b.x;
        o.y = nd * ay + b.y;
        o.z = nd * az + b.z;
        o.w = nd * aw + b.w;
        if (RELU) {
            o.x = fmaxf(o.x, 0.f); o.y = fmaxf(o.y, 0.f);
            o.z = fmaxf(o.z, 0.f); o.w = fmaxf(o.w, 0.f);
        }
        *(float4*)(out + (size_t)v * 128 + fb) = o;
    }
}

template <bool RELU>
__global__ __launch_bounds__(256) void aggregate2(
    const float* __restrict__ Tm, const int* __restrict__ row_off,
    const int* __restrict__ csr, const float* __restrict__ ndst,
    const float* __restrict__ bias, float* __restrict__ out, int n)
{
    int lane = threadIdx.x & 31;
    int team = threadIdx.x >> 5;
    int fb = lane * 2;
    float2 b = *(const float2*)(bias + fb);
    int stride = gridDim.x * 8;
    for (int v = blockIdx.x * 8 + team; v < n; v += stride) {
        int s = row_off[v], e = row_off[v + 1];
        float nd = ndst[v];
        float ax = 0.f, ay = 0.f;
        int i = s;
        for (; i + 4 <= e; i += 4) {
            int u0 = csr[i], u1 = csr[i + 1], u2 = csr[i + 2], u3 = csr[i + 3];
            float2 t0 = *(const float2*)(Tm + (size_t)u0 * 64 + fb);
            float2 t1 = *(const float2*)(Tm + (size_t)u1 * 64 + fb);
            float2 t2 = *(const float2*)(Tm + (size_t)u2 * 64 + fb);
            float2 t3 = *(const float2*)(Tm + (size_t)u3 * 64 + fb);
            ax += (t0.x + t1.x) + (t2.x + t3.x);
            ay += (t0.y + t1.y) + (t2.y + t3.y);
        }
        for (; i < e; i++) {
            int u = csr[i];
            float2 t0 = *(const float2*)(Tm + (size_t)u * 64 + fb);
            ax += t0.x; ay += t0.y;
        }
        float2 o;
        o.x = nd * ax + b.x;
        o.y = nd * ay + b.y;
        if (RELU) { o.x = fmaxf(o.x, 0.f); o.y = fmaxf(o.y, 0.f); }
        *(float2*)(out + (size_t)v * 64 + fb) = o;
    }
}

// ---------------- launch ----------------
extern "C" void kernel_launch(void* const* d_in, const int* in_sizes, int n_in,
                              void* d_out, int out_size, void* d_ws, size_t ws_size,
                              hipStream_t stream)
{
    const float* features = (const float*)d_in[0];
    const int* src = (const int*)d_in[1];
    const int* dst = (const int*)d_in[2];
    const float* W0 = (const float*)d_in[3];
    const float* b0 = (const float*)d_in[4];
    const float* W1 = (const float*)d_in[5];
    const float* b1 = (const float*)d_in[6];
    const float* W2 = (const float*)d_in[7];
    const float* b2 = (const float*)d_in[8];

    int n = in_sizes[0] / K_FEATS;  // 100000
    int ne = in_sizes[1];           // 1600000

    char* ws = (char*)d_ws;
    size_t off = 0;
    auto take = [&](size_t bytes) -> char* {
        char* p = ws + off;
        off = (off + bytes + 255) & ~(size_t)255;
        return p;
    };
    float* bufA = (float*)take((size_t)n * 128 * 4);
    float* bufB = (float*)take((size_t)n * 128 * 4);
    int* deg_out = (int*)take((size_t)n * 4);
    int* deg_in = (int*)take((size_t)n * 4);
    int* cursor = (int*)take((size_t)n * 4);
    int* row_off = (int*)take((size_t)(n + 1) * 4);
    int* partial = (int*)take(1024 * 4);
    float* norm_src = (float*)take((size_t)n * 4);
    float* norm_dst = (float*)take((size_t)n * 4);
    int* csr = (int*)take((size_t)ne * 4);

    hipMemsetAsync(deg_out, 0, (size_t)n * 4, stream);
    hipMemsetAsync(deg_in, 0, (size_t)n * 4, stream);
    hipMemsetAsync(cursor, 0, (size_t)n * 4, stream);

    hist_kernel<<<2048, 256, 0, stream>>>(src, dst, deg_out, deg_in, ne);
    norms_kernel<<<(n + 255) / 256, 256, 0, stream>>>(deg_out, deg_in, norm_src,
                                                      norm_dst, row_off, n, ne);
    int nb = (n + SCAN_CHUNK - 1) / SCAN_CHUNK;
    scan_a<<<nb, 256, 0, stream>>>(deg_in, partial, n);
    scan_b<<<1, 64, 0, stream>>>(partial, nb);
    scan_c<<<nb, 256, 0, stream>>>(deg_in, partial, row_off, n);
    fill_csr<<<2048, 256, 0, stream>>>(src, dst, row_off, cursor, csr, ne);

    int gblocks = (n + 127) / 128;
    int ablocks = (n + 7) / 8;

    // layer 0: T = Nsrc ⊙ (X @ W0); h = relu(Ndst ⊙ A·T + b0)
    gemm_scale<128><<<gblocks, 256, 0, stream>>>(features, W0, norm_src, bufA, n);
    aggregate4<true><<<ablocks, 256, 0, stream>>>(bufA, row_off, csr, norm_dst, b0, bufB, n);
    // layer 1
    gemm_scale<128><<<gblocks, 256, 0, stream>>>(bufB, W1, norm_src, bufA, n);
    aggregate4<true><<<ablocks, 256, 0, stream>>>(bufA, row_off, csr, norm_dst, b1, bufB, n);
    // layer 2 (M=64, no relu) -> d_out
    gemm_scale<64><<<gblocks, 256, 0, stream>>>(bufB, W2, norm_src, bufA, n);
    aggregate2<false><<<ablocks, 256, 0, stream>>>(bufA, row_off, csr, norm_dst, b2,
                                                   (float*)d_out, n);
}

// Round 2
// 770.452 us; speedup vs baseline: 1.0229x; 1.0229x over previous
//
#include <hip/hip_runtime.h>

#define K_FEATS 128
#define SCAN_CHUNK 1024
#define BPR 16384     // bins per range: 64 KB LDS histogram
#define NCHUNK 32     // edge chunks

// ---------------- per-chunk LDS histograms (no global atomics) ----------------
// blockIdx = (chunk c, range r, array a: 0=src,1=dst)
__global__ __launch_bounds__(256) void count_kernel(
    const int* __restrict__ src, const int* __restrict__ dst,
    int* __restrict__ partial_out, int* __restrict__ partial_in,
    int ne, int chunk, int nstride, int n)
{
    __shared__ int h[BPR];
    int c = blockIdx.x, r = blockIdx.y, a = blockIdx.z;
    const int* idx = a ? dst : src;
    int* part = a ? partial_in : partial_out;
    for (int i = threadIdx.x; i < BPR; i += 256) h[i] = 0;
    __syncthreads();
    int lo = r * BPR;
    int e0 = c * chunk, e1 = min(ne, e0 + chunk);
    for (int e = e0 + threadIdx.x; e < e1; e += 256) {
        int b = idx[e] - lo;
        if ((unsigned)b < (unsigned)BPR) atomicAdd(&h[b], 1);
    }
    __syncthreads();
    for (int i = threadIdx.x; i < BPR; i += 256) {
        int gb = lo + i;
        if (gb < n) part[(size_t)c * nstride + gb] = h[i];
    }
}

// ---------------- reduce partials -> degrees, norms; in-place chunk prefix ----
__global__ __launch_bounds__(256) void reduce_prefix(
    int* __restrict__ partial_in, const int* __restrict__ partial_out,
    int* __restrict__ deg_in, float* __restrict__ norm_src,
    float* __restrict__ norm_dst, int* __restrict__ row_off,
    int nstride, int n, int ne)
{
    int i = blockIdx.x * 256 + threadIdx.x;
    if (i == 0) row_off[n] = ne;
    if (i >= n) return;
    int run = 0;
#pragma unroll 4
    for (int c = 0; c < NCHUNK; c++) {
        size_t p = (size_t)c * nstride + i;
        int v = partial_in[p];
        partial_in[p] = run;   // exclusive prefix over chunks
        run += v;
    }
    deg_in[i] = run;
    norm_dst[i] = rsqrtf((float)max(run, 1));
    int s = 0;
#pragma unroll 4
    for (int c = 0; c < NCHUNK; c++) s += partial_out[(size_t)c * nstride + i];
    norm_src[i] = rsqrtf((float)max(s, 1));
}

// ---------------- 3-phase exclusive scan of deg_in -> row_off ----------------
__global__ __launch_bounds__(256) void scan_a(const int* __restrict__ deg,
                                              int* __restrict__ partial, int n)
{
    __shared__ int sh[256];
    int t = threadIdx.x;
    int base = blockIdx.x * SCAN_CHUNK + t * 4;
    int s = 0;
#pragma unroll
    for (int j = 0; j < 4; j++)
        if (base + j < n) s += deg[base + j];
    sh[t] = s;
    __syncthreads();
    for (int off = 128; off > 0; off >>= 1) {
        if (t < off) sh[t] += sh[t + off];
        __syncthreads();
    }
    if (t == 0) partial[blockIdx.x] = sh[0];
}

__global__ void scan_b(int* __restrict__ partial, int nb)
{
    if (threadIdx.x == 0) {
        int run = 0;
        for (int i = 0; i < nb; i++) {
            int v = partial[i];
            partial[i] = run;
            run += v;
        }
    }
}

__global__ __launch_bounds__(256) void scan_c(const int* __restrict__ deg,
                                              const int* __restrict__ partial,
                                              int* __restrict__ row_off, int n)
{
    __shared__ int sh[256];
    int t = threadIdx.x;
    int base = blockIdx.x * SCAN_CHUNK + t * 4;
    int v[4];
    int s = 0;
#pragma unroll
    for (int j = 0; j < 4; j++) {
        v[j] = (base + j < n) ? deg[base + j] : 0;
        s += v[j];
    }
    sh[t] = s;
    __syncthreads();
    for (int off = 1; off < 256; off <<= 1) {
        int x = (t >= off) ? sh[t - off] : 0;
        __syncthreads();
        sh[t] += x;
        __syncthreads();
    }
    int excl = sh[t] - s + partial[blockIdx.x];
#pragma unroll
    for (int j = 0; j < 4; j++) {
        if (base + j < n) row_off[base + j] = excl;
        excl += v[j];
    }
}

// ---------------- CSR fill via LDS cursors (no global atomics) ----------------
__global__ __launch_bounds__(256) void scatter_kernel(
    const int* __restrict__ src, const int* __restrict__ dst,
    const int* __restrict__ row_off, const int* __restrict__ prefix_in,
    int* __restrict__ csr, int ne, int chunk, int nstride, int n)
{
    __shared__ int cur[BPR];
    int c = blockIdx.x, r = blockIdx.y;
    int lo = r * BPR;
    for (int i = threadIdx.x; i < BPR; i += 256) {
        int gb = lo + i;
        cur[i] = (gb < n) ? row_off[gb] + prefix_in[(size_t)c * nstride + gb] : 0;
    }
    __syncthreads();
    int e0 = c * chunk, e1 = min(ne, e0 + chunk);
    for (int e = e0 + threadIdx.x; e < e1; e += 256) {
        int d = dst[e] - lo;
        if ((unsigned)d < (unsigned)BPR) {
            int pos = atomicAdd(&cur[d], 1);
            csr[pos] = src[e];
        }
    }
}

// ---------------- GEMM: T = rowscale ⊙ (X @ W), K=128, M in {128,64} ----------------
template <int M>
__global__ __launch_bounds__(256) void gemm_scale(
    const float* __restrict__ X, const float* __restrict__ W,
    const float* __restrict__ scale, float* __restrict__ T, int n)
{
    constexpr int KC = 16;
    constexpr int CT = M / 8;       // col-threads: 16 (M=128) or 8 (M=64)
    constexpr int RT = 256 / CT;    // row-threads: 16 or 32
    constexpr int RPT = 128 / RT;   // rows per thread: 8 or 4
    constexpr int XPITCH = 132;     // pad: conflict-free reads, 16B-aligned

    __shared__ float Ws[K_FEATS * M];
    __shared__ float Xs[KC * XPITCH];

    int t = threadIdx.x;
    int tc = t % CT;
    int tr = t / CT;
    int block_row = blockIdx.x * 128;

    // stage full W into LDS (row-major [128][M]), contiguous float4 stores
#pragma unroll
    for (int i = 0; i < M / 8; i++) {
        int idx4 = t + i * 256;
        ((float4*)Ws)[idx4] = ((const float4*)W)[idx4];
    }

    float acc[RPT][8] = {};

    for (int k0 = 0; k0 < K_FEATS; k0 += KC) {
        // stage X chunk transposed: Xs[kk][row], 128 rows x KC cols
#pragma unroll
        for (int i = 0; i < (128 * KC) / (256 * 4); i++) {  // 2 float4 per thread
            int idx4 = t + i * 256;       // over [128][KC/4]
            int r = idx4 / (KC / 4);
            int c4 = idx4 % (KC / 4);
            int gr = block_row + r;
            float4 v = make_float4(0.f, 0.f, 0.f, 0.f);
            if (gr < n) v = *(const float4*)(X + (size_t)gr * K_FEATS + k0 + c4 * 4);
            Xs[(c4 * 4 + 0) * XPITCH + r] = v.x;
            Xs[(c4 * 4 + 1) * XPITCH + r] = v.y;
            Xs[(c4 * 4 + 2) * XPITCH + r] = v.z;
            Xs[(c4 * 4 + 3) * XPITCH + r] = v.w;
        }
        __syncthreads();
#pragma unroll 8
        for (int kk = 0; kk < KC; kk++) {
            float4 w0 = *(const float4*)&Ws[(k0 + kk) * M + 8 * tc];
            float4 w1 = *(const float4*)&Ws[(k0 + kk) * M + 8 * tc + 4];
            float xr[RPT];
#pragma unroll
            for (int g = 0; g < RPT / 4; g++) {
                float4 xa = *(const float4*)&Xs[kk * XPITCH + 4 * tr + g * (4 * RT)];
                xr[g * 4 + 0] = xa.x;
                xr[g * 4 + 1] = xa.y;
                xr[g * 4 + 2] = xa.z;
                xr[g * 4 + 3] = xa.w;
            }
#pragma unroll
            for (int i = 0; i < RPT; i++) {
                acc[i][0] += xr[i] * w0.x;
                acc[i][1] += xr[i] * w0.y;
                acc[i][2] += xr[i] * w0.z;
                acc[i][3] += xr[i] * w0.w;
                acc[i][4] += xr[i] * w1.x;
                acc[i][5] += xr[i] * w1.y;
                acc[i][6] += xr[i] * w1.z;
                acc[i][7] += xr[i] * w1.w;
            }
        }
        __syncthreads();
    }

    // epilogue: scale row by norm_src and store
#pragma unroll
    for (int i = 0; i < RPT; i++) {
        int r = block_row + 4 * tr + (i & 3) + (i >> 2) * (4 * RT);
        if (r < n) {
            float s = scale[r];
            float4 o0 = make_float4(acc[i][0] * s, acc[i][1] * s, acc[i][2] * s, acc[i][3] * s);
            float4 o1 = make_float4(acc[i][4] * s, acc[i][5] * s, acc[i][6] * s, acc[i][7] * s);
            *(float4*)(T + (size_t)r * M + 8 * tc) = o0;
            *(float4*)(T + (size_t)r * M + 8 * tc + 4) = o1;
        }
    }
}

// ---------------- aggregation: out[v] = act( ndst[v]*sum_{u in N(v)} T[u] + b ) ----------------
template <bool RELU>
__global__ __launch_bounds__(256) void aggregate4(
    const float* __restrict__ Tm, const int* __restrict__ row_off,
    const int* __restrict__ csr, const float* __restrict__ ndst,
    const float* __restrict__ bias, float* __restrict__ out, int n)
{
    int lane = threadIdx.x & 31;
    int team = threadIdx.x >> 5;
    int fb = lane * 4;
    float4 b = *(const float4*)(bias + fb);
    int stride = gridDim.x * 8;
    for (int v = blockIdx.x * 8 + team; v < n; v += stride) {
        int s = row_off[v], e = row_off[v + 1];
        float nd = ndst[v];
        float ax = 0.f, ay = 0.f, az = 0.f, aw = 0.f;
        int i = s;
        for (; i + 4 <= e; i += 4) {
            int u0 = csr[i], u1 = csr[i + 1], u2 = csr[i + 2], u3 = csr[i + 3];
            float4 t0 = *(const float4*)(Tm + (size_t)u0 * 128 + fb);
            float4 t1 = *(const float4*)(Tm + (size_t)u1 * 128 + fb);
            float4 t2 = *(const float4*)(Tm + (size_t)u2 * 128 + fb);
            float4 t3 = *(const float4*)(Tm + (size_t)u3 * 128 + fb);
            ax += (t0.x + t1.x) + (t2.x + t3.x);
            ay += (t0.y + t1.y) + (t2.y + t3.y);
            az += (t0.z + t1.z) + (t2.z + t3.z);
            aw += (t0.w + t1.w) + (t2.w + t3.w);
        }
        for (; i < e; i++) {
            int u = csr[i];
            float4 t0 = *(const float4*)(Tm + (size_t)u * 128 + fb);
            ax += t0.x; ay += t0.y; az += t0.z; aw += t0.w;
        }
        float4 o;
        o.x = nd * ax + b.x;
        o.y = nd * ay + b.y;
        o.z = nd * az + b.z;
        o.w = nd * aw + b.w;
        if (RELU) {
            o.x = fmaxf(o.x, 0.f); o.y = fmaxf(o.y, 0.f);
            o.z = fmaxf(o.z, 0.f); o.w = fmaxf(o.w, 0.f);
        }
        *(float4*)(out + (size_t)v * 128 + fb) = o;
    }
}

template <bool RELU>
__global__ __launch_bounds__(256) void aggregate2(
    const float* __restrict__ Tm, const int* __restrict__ row_off,
    const int* __restrict__ csr, const float* __restrict__ ndst,
    const float* __restrict__ bias, float* __restrict__ out, int n)
{
    int lane = threadIdx.x & 31;
    int team = threadIdx.x >> 5;
    int fb = lane * 2;
    float2 b = *(const float2*)(bias + fb);
    int stride = gridDim.x * 8;
    for (int v = blockIdx.x * 8 + team; v < n; v += stride) {
        int s = row_off[v], e = row_off[v + 1];
        float nd = ndst[v];
        float ax = 0.f, ay = 0.f;
        int i = s;
        for (; i + 4 <= e; i += 4) {
            int u0 = csr[i], u1 = csr[i + 1], u2 = csr[i + 2], u3 = csr[i + 3];
            float2 t0 = *(const float2*)(Tm + (size_t)u0 * 64 + fb);
            float2 t1 = *(const float2*)(Tm + (size_t)u1 * 64 + fb);
            float2 t2 = *(const float2*)(Tm + (size_t)u2 * 64 + fb);
            float2 t3 = *(const float2*)(Tm + (size_t)u3 * 64 + fb);
            ax += (t0.x + t1.x) + (t2.x + t3.x);
            ay += (t0.y + t1.y) + (t2.y + t3.y);
        }
        for (; i < e; i++) {
            int u = csr[i];
            float2 t0 = *(const float2*)(Tm + (size_t)u * 64 + fb);
            ax += t0.x; ay += t0.y;
        }
        float2 o;
        o.x = nd * ax + b.x;
        o.y = nd * ay + b.y;
        if (RELU) { o.x = fmaxf(o.x, 0.f); o.y = fmaxf(o.y, 0.f); }
        *(float2*)(out + (size_t)v * 64 + fb) = o;
    }
}

// ---------------- launch ----------------
extern "C" void kernel_launch(void* const* d_in, const int* in_sizes, int n_in,
                              void* d_out, int out_size, void* d_ws, size_t ws_size,
                              hipStream_t stream)
{
    const float* features = (const float*)d_in[0];
    const int* src = (const int*)d_in[1];
    const int* dst = (const int*)d_in[2];
    const float* W0 = (const float*)d_in[3];
    const float* b0 = (const float*)d_in[4];
    const float* W1 = (const float*)d_in[5];
    const float* b1 = (const float*)d_in[6];
    const float* W2 = (const float*)d_in[7];
    const float* b2 = (const float*)d_in[8];

    int n = in_sizes[0] / K_FEATS;  // 100000
    int ne = in_sizes[1];           // 1600000

    char* ws = (char*)d_ws;
    size_t off = 0;
    auto take = [&](size_t bytes) -> char* {
        char* p = ws + off;
        off = (off + bytes + 255) & ~(size_t)255;
        return p;
    };
    float* bufA = (float*)take((size_t)n * 128 * 4);
    float* bufB = (float*)take((size_t)n * 128 * 4);
    int* deg_in = (int*)take((size_t)n * 4);
    int* row_off = (int*)take((size_t)(n + 1) * 4);
    int* partial = (int*)take(1024 * 4);
    float* norm_src = (float*)take((size_t)n * 4);
    float* norm_dst = (float*)take((size_t)n * 4);
    int* csr = (int*)take((size_t)ne * 4);

    // partial histogram arrays overlay bufA/bufB (only live before first GEMM)
    int nstride = (n + 63) & ~63;
    int* partial_in = (int*)bufA;   // NCHUNK * nstride ints  (12.8 MB < 51.2 MB)
    int* partial_out = (int*)bufB;

    int chunk = (ne + NCHUNK - 1) / NCHUNK;
    int R = (n + BPR - 1) / BPR;    // 7 ranges

    count_kernel<<<dim3(NCHUNK, R, 2), 256, 0, stream>>>(
        src, dst, partial_out, partial_in, ne, chunk, nstride, n);
    reduce_prefix<<<(n + 255) / 256, 256, 0, stream>>>(
        partial_in, partial_out, deg_in, norm_src, norm_dst, row_off, nstride, n, ne);
    int nb = (n + SCAN_CHUNK - 1) / SCAN_CHUNK;
    scan_a<<<nb, 256, 0, stream>>>(deg_in, partial, n);
    scan_b<<<1, 64, 0, stream>>>(partial, nb);
    scan_c<<<nb, 256, 0, stream>>>(deg_in, partial, row_off, n);
    scatter_kernel<<<dim3(NCHUNK, R), 256, 0, stream>>>(
        src, dst, row_off, partial_in, csr, ne, chunk, nstride, n);

    int gblocks = (n + 127) / 128;
    int ablocks = (n + 7) / 8;

    // layer 0: T = Nsrc ⊙ (X @ W0); h = relu(Ndst ⊙ A·T + b0)
    gemm_scale<128><<<gblocks, 256, 0, stream>>>(features, W0, norm_src, bufA, n);
    aggregate4<true><<<ablocks, 256, 0, stream>>>(bufA, row_off, csr, norm_dst, b0, bufB, n);
    // layer 1
    gemm_scale<128><<<gblocks, 256, 0, stream>>>(bufB, W1, norm_src, bufA, n);
    aggregate4<true><<<ablocks, 256, 0, stream>>>(bufA, row_off, csr, norm_dst, b1, bufB, n);
    // layer 2 (M=64, no relu) -> d_out
    gemm_scale<64><<<gblocks, 256, 0, stream>>>(bufB, W2, norm_src, bufA, n);
    aggregate2<false><<<ablocks, 256, 0, stream>>>(bufA, row_off, csr, norm_dst, b2,
                                                   (float*)d_out, n);
}